// Round 1
// baseline (761.657 us; speedup 1.0000x reference)
//
#include <hip/hip_runtime.h>
#include <stdint.h>

// ---------------------------------------------------------------------------
// GroupedQueryAttention: hidden(B,S,4096) -> QKV proj -> RoPE -> causal GQA
// attention -> out proj.  B=2 S=2048 H=32 Hk=8 D=128.  All internal matmuls
// in bf16 MFMA (threshold is 2% of ref absmax = bf16-grade).
// ---------------------------------------------------------------------------

#define HIDDEN 4096
#define NH 32
#define NKV 8
#define HD 128
#define SLEN 2048
#define BATCH 2

typedef __attribute__((ext_vector_type(8))) short bf16x8;
typedef __attribute__((ext_vector_type(4))) float f32x4;

__device__ __forceinline__ unsigned short f2bf(float f) {
  union { float f; uint32_t u; } v; v.f = f;
  uint32_t u = v.u;
  uint32_t r = (u + 0x7FFFu + ((u >> 16) & 1u)) >> 16;  // RNE
  return (unsigned short)r;
}
__device__ __forceinline__ float bf2f(unsigned short h) {
  union { uint32_t u; float f; } v; v.u = ((uint32_t)h) << 16;
  return v.f;
}
__device__ __forceinline__ void gload_lds16(const void* g, void* l) {
  __builtin_amdgcn_global_load_lds(
      (const __attribute__((address_space(1))) unsigned int*)g,
      (__attribute__((address_space(3))) unsigned int*)l, 16, 0, 0);
}

// ---------------------------------------------------------------------------
// fp32 -> bf16 convert, 8 elems/thread (G13). Grid sized exactly: n = grid*2048.
// ---------------------------------------------------------------------------
__global__ __launch_bounds__(256) void cvt_f32_bf16(const float* __restrict__ in,
                                                    unsigned short* __restrict__ out) {
  size_t i = ((size_t)blockIdx.x * 256 + threadIdx.x) * 8;
  f32x4 a = *(const f32x4*)&in[i];
  f32x4 b = *(const f32x4*)&in[i + 4];
  bf16x8 o;
#pragma unroll
  for (int j = 0; j < 4; ++j) { o[j] = (short)f2bf(a[j]); o[4 + j] = (short)f2bf(b[j]); }
  *(bf16x8*)&out[i] = o;
}

// ---------------------------------------------------------------------------
// GEMM  C(M,N) = A(M,K) @ B(N,K)^T, bf16 in, OutT out.  m97 structure:
// 128x128 tile, BK=32, 4 waves (2x2, 64x64 each), global_load_lds width 16.
// M,N multiples of 128; K multiple of 32; grid multiple of 8 (XCD swizzle).
// ---------------------------------------------------------------------------
__device__ __forceinline__ void store_out(unsigned short* C, size_t i, float v) { C[i] = f2bf(v); }
__device__ __forceinline__ void store_out(float* C, size_t i, float v) { C[i] = v; }

template <typename OutT>
__global__ __launch_bounds__(256, 2)
void gemm_bt(const unsigned short* __restrict__ A, const unsigned short* __restrict__ B,
             OutT* __restrict__ C, int M, int N, int K) {
  __shared__ __align__(16) unsigned short Asm[128 * 32];
  __shared__ __align__(16) unsigned short Bsm[128 * 32];
  const int tid = threadIdx.x;
  const int lane = tid & 63, wid = tid >> 6;
  const int lr = lane & 15, lg = lane >> 4;
  const int wr = wid >> 1, wc = wid & 1;

  const int nbn = N >> 7;
  const int nwg = gridDim.x;
  int wg = (int)blockIdx.x;
  wg = (wg & 7) * (nwg >> 3) + (wg >> 3);  // XCD-aware swizzle (nwg%8==0)
  const int bm = wg / nbn, bn = wg % nbn;

  const unsigned short* Ab = A + (size_t)bm * 128 * K;
  const unsigned short* Bb = B + (size_t)bn * 128 * K;

  f32x4 acc[4][4] = {};

  const int c0 = tid, c1 = tid + 256;            // chunk = 16B = 8 bf16
  const int ar0 = c0 >> 2, ak0 = (c0 & 3) * 8;   // 4 chunks per 32-wide row
  const int ar1 = c1 >> 2, ak1 = (c1 & 3) * 8;

  for (int kt = 0; kt < K; kt += 32) {
    __syncthreads();
    gload_lds16(Ab + (size_t)ar0 * K + kt + ak0, &Asm[c0 * 8]);
    gload_lds16(Ab + (size_t)ar1 * K + kt + ak1, &Asm[c1 * 8]);
    gload_lds16(Bb + (size_t)ar0 * K + kt + ak0, &Bsm[c0 * 8]);
    gload_lds16(Bb + (size_t)ar1 * K + kt + ak1, &Bsm[c1 * 8]);
    __syncthreads();

    bf16x8 af[4], bfr[4];
#pragma unroll
    for (int mi = 0; mi < 4; ++mi)
      af[mi] = *(const bf16x8*)&Asm[(wr * 64 + mi * 16 + lr) * 32 + lg * 8];
#pragma unroll
    for (int ni = 0; ni < 4; ++ni)
      bfr[ni] = *(const bf16x8*)&Bsm[(wc * 64 + ni * 16 + lr) * 32 + lg * 8];
#pragma unroll
    for (int mi = 0; mi < 4; ++mi)
#pragma unroll
      for (int ni = 0; ni < 4; ++ni)
        acc[mi][ni] = __builtin_amdgcn_mfma_f32_16x16x32_bf16(af[mi], bfr[ni], acc[mi][ni], 0, 0, 0);
  }

#pragma unroll
  for (int mi = 0; mi < 4; ++mi)
#pragma unroll
    for (int ni = 0; ni < 4; ++ni)
#pragma unroll
      for (int r = 0; r < 4; ++r) {
        size_t row = (size_t)bm * 128 + wr * 64 + mi * 16 + lg * 4 + r;
        size_t col = (size_t)bn * 128 + wc * 64 + ni * 16 + lr;
        store_out(C, row * N + col, acc[mi][ni][r]);
      }
}

// ---------------------------------------------------------------------------
// RoPE tables: ct/st (S,64) fp32.  inv_freq = 10000^(-j/64).
// ---------------------------------------------------------------------------
__global__ __launch_bounds__(256) void rope_tables(float* __restrict__ ct, float* __restrict__ st) {
  int idx = blockIdx.x * 256 + threadIdx.x;  // S*64
  int s = idx >> 6, j = idx & 63;
  float inv = exp2f(-(float)j * (13.287712379549449f / 64.f));
  float f = (float)s * inv;
  ct[idx] = cosf(f);
  st[idx] = sinf(f);
}

// RoPE apply in-place on X (B*S, heads*128).  Thread: one (row, head, 8-chunk of j).
__global__ __launch_bounds__(256) void rope_apply(unsigned short* __restrict__ X,
                                                  const float* __restrict__ ct,
                                                  const float* __restrict__ st, int heads) {
  int idx = blockIdx.x * 256 + threadIdx.x;
  int jc = (idx & 7) * 8;
  int t2 = idx >> 3;
  int hh = t2 % heads;
  int row = t2 / heads;
  int s = row & (SLEN - 1);
  unsigned short* p = X + ((size_t)row * heads + hh) * HD;
  bf16x8 lo = *(bf16x8*)&p[jc];
  bf16x8 hi = *(bf16x8*)&p[64 + jc];
  bf16x8 nlo, nhi;
#pragma unroll
  for (int j = 0; j < 8; ++j) {
    float c = ct[s * 64 + jc + j];
    float sn = st[s * 64 + jc + j];
    float xl = bf2f((unsigned short)(lo[j]));
    float xh = bf2f((unsigned short)(hi[j]));
    nlo[j] = (short)f2bf(xl * c - xh * sn);
    nhi[j] = (short)f2bf(xh * c + xl * sn);
  }
  *(bf16x8*)&p[jc] = nlo;
  *(bf16x8*)&p[64 + jc] = nhi;
}

// ---------------------------------------------------------------------------
// V (B*S, NKV*HD) -> VT (B, NKV, HD, S): LDS 64x64 tile transpose.
// ---------------------------------------------------------------------------
__global__ __launch_bounds__(256) void transpose_v(const unsigned short* __restrict__ V,
                                                   unsigned short* __restrict__ VT) {
  __shared__ unsigned short tile[64][66];
  const int t = threadIdx.x;
  const int bs = blockIdx.x;  // B * S/64 = 64
  const int bd = blockIdx.y;  // 1024/64  = 16
  const int b = bs >> 5;
  const int s0 = (bs & 31) * 64;
  const int d0 = bd * 64;
#pragma unroll
  for (int it = 0; it < 2; ++it) {
    int si = (t >> 3) + it * 32;
    int dj = (t & 7) * 8;
    bf16x8 v = *(const bf16x8*)&V[(size_t)(b * SLEN + s0 + si) * (NKV * HD) + d0 + dj];
#pragma unroll
    for (int j = 0; j < 8; ++j) tile[si][dj + j] = (unsigned short)(v[j]);
  }
  __syncthreads();
#pragma unroll
  for (int it = 0; it < 2; ++it) {
    int di = (t >> 3) + it * 32;
    int sj = (t & 7) * 8;
    bf16x8 o;
#pragma unroll
    for (int j = 0; j < 8; ++j) o[j] = (short)tile[sj + j][di];
    int c = d0 + di;
    int kvh = c >> 7, d = c & 127;
    *(bf16x8*)&VT[(((size_t)b * NKV + kvh) * HD + d) * SLEN + s0 + sj] = o;
  }
}

// ---------------------------------------------------------------------------
// Flash attention.  Block = (qt, kvh, b); 4 waves = 4 q-heads of this kv head,
// each wave: 32 q rows x full D.  K tile [64][128+8] and VT tile [128][64+8]
// staged cooperatively (padded rows -> <=2-way LDS bank aliasing).
// Swapped QK^T: S^T = mfma(K, Q) so softmax reduce = regs + 2 shfl_xor.
// P goes through per-wave padded LDS into A-layout for PV.
// ---------------------------------------------------------------------------
__global__ __launch_bounds__(256, 2)
void attn_fwd(const unsigned short* __restrict__ Qm, const unsigned short* __restrict__ Km,
              const unsigned short* __restrict__ VTm, unsigned short* __restrict__ Om) {
  const int qt = blockIdx.x;   // S/32
  const int kvh = blockIdx.y;  // NKV
  const int b = blockIdx.z;    // B
  const int tid = threadIdx.x;
  const int lane = tid & 63, w = tid >> 6;
  const int lr = lane & 15, lg = lane >> 4;
  const int h = kvh * 4 + w;
  const int q0 = qt * 32;

  __shared__ __align__(16) unsigned short Ksm[64 * 136];   // [key][d], pad +8
  __shared__ __align__(16) unsigned short Vsm[128 * 72];   // [d][key], pad +8
  __shared__ __align__(16) unsigned short Psm[4][32 * 72]; // per-wave [q][key], pad +8
  __shared__ __align__(16) float Alds[4][32];

  const float SCALE = 0.08838834764831845f;  // 1/sqrt(128)
  const float LOG2E = 1.4426950408889634f;

  // hoist Q fragments (B-operand of swapped QK^T): q = ni*16+lr, d = kd*32+lg*8
  bf16x8 qf[2][4];
  const unsigned short* Qb = Qm + ((size_t)(b * SLEN + q0) * NH + h) * HD;
#pragma unroll
  for (int ni = 0; ni < 2; ++ni)
#pragma unroll
    for (int kd = 0; kd < 4; ++kd)
      qf[ni][kd] = *(const bf16x8*)&Qb[(size_t)(ni * 16 + lr) * (NH * HD) + kd * 32 + lg * 8];

  f32x4 acc_o[2][8] = {};
  float m_run[2] = {-1e30f, -1e30f};
  float l_run[2] = {0.f, 0.f};

  const unsigned short* Kb0 = Km + ((size_t)(b * SLEN) * NKV + kvh) * HD;
  const unsigned short* VTb = VTm + ((size_t)(b * NKV + kvh) * HD) * SLEN;

  const int ntiles = q0 / 64 + 1;
  for (int t = 0; t < ntiles; ++t) {
    const int kv0 = t * 64;
    __syncthreads();
    // stage K 64x128 and VT 128x64 (1024 16B-chunks each, 4 per thread)
#pragma unroll
    for (int i = 0; i < 4; ++i) {
      int c = tid + i * 256;
      int key = c >> 4, dc = (c & 15) * 8;
      *(bf16x8*)&Ksm[key * 136 + dc] =
          *(const bf16x8*)&Kb0[(size_t)(kv0 + key) * (NKV * HD) + dc];
      int d = c >> 3, kc = (c & 7) * 8;
      *(bf16x8*)&Vsm[d * 72 + kc] = *(const bf16x8*)&VTb[(size_t)d * SLEN + kv0 + kc];
    }
    __syncthreads();

    // S^T(64 key x 32 q) = K @ Q^T
    f32x4 accs[4][2] = {};
#pragma unroll
    for (int kd = 0; kd < 4; ++kd) {
      bf16x8 kf[4];
#pragma unroll
      for (int mi = 0; mi < 4; ++mi)
        kf[mi] = *(const bf16x8*)&Ksm[(mi * 16 + lr) * 136 + kd * 32 + lg * 8];
#pragma unroll
      for (int mi = 0; mi < 4; ++mi)
#pragma unroll
        for (int ni = 0; ni < 2; ++ni)
          accs[mi][ni] =
              __builtin_amdgcn_mfma_f32_16x16x32_bf16(kf[mi], qf[ni][kd], accs[mi][ni], 0, 0, 0);
    }

    const bool domask = (t == ntiles - 1);  // earlier tiles are fully in-range
#pragma unroll
    for (int ni = 0; ni < 2; ++ni) {
      float cmax = -1e30f;
#pragma unroll
      for (int mi = 0; mi < 4; ++mi)
#pragma unroll
        for (int r = 0; r < 4; ++r) {
          float s = accs[mi][ni][r] * SCALE;
          if (domask) {
            int key = kv0 + mi * 16 + lg * 4 + r;
            int qq = q0 + ni * 16 + lr;
            if (key > qq) s = -1e30f;
          }
          accs[mi][ni][r] = s;
          cmax = fmaxf(cmax, s);
        }
      cmax = fmaxf(cmax, __shfl_xor(cmax, 16));
      cmax = fmaxf(cmax, __shfl_xor(cmax, 32));
      float mnew = fmaxf(m_run[ni], cmax);
      float alpha = exp2f((m_run[ni] - mnew) * LOG2E);
      float psum = 0.f;
#pragma unroll
      for (int mi = 0; mi < 4; ++mi)
#pragma unroll
        for (int r = 0; r < 4; ++r) {
          float p = exp2f((accs[mi][ni][r] - mnew) * LOG2E);
          accs[mi][ni][r] = p;
          psum += p;
        }
      psum += __shfl_xor(psum, 16);
      psum += __shfl_xor(psum, 32);
      l_run[ni] = l_run[ni] * alpha + psum;
      m_run[ni] = mnew;
      if (lg == 0) Alds[w][ni * 16 + lr] = alpha;  // per-q rescale factor
    }

    // rescale O by alpha (transposed via LDS: O rows are q = pm*16 + lg*4 + r)
    f32x4 al0 = *(const f32x4*)&Alds[w][lg * 4];
    f32x4 al1 = *(const f32x4*)&Alds[w][16 + lg * 4];
#pragma unroll
    for (int nd = 0; nd < 8; ++nd)
#pragma unroll
      for (int r = 0; r < 4; ++r) {
        acc_o[0][nd][r] *= al0[r];
        acc_o[1][nd][r] *= al1[r];
      }

    // P (S^T layout: row=key=mi*16+lg*4+r, col=q=ni*16+lr) -> Psm[q][key] bf16
#pragma unroll
    for (int ni = 0; ni < 2; ++ni)
#pragma unroll
      for (int mi = 0; mi < 4; ++mi)
#pragma unroll
        for (int rp = 0; rp < 4; rp += 2) {
          uint32_t pk = (uint32_t)f2bf(accs[mi][ni][rp]) |
                        ((uint32_t)f2bf(accs[mi][ni][rp + 1]) << 16);
          *(uint32_t*)&Psm[w][(ni * 16 + lr) * 72 + mi * 16 + lg * 4 + rp] = pk;
        }

    // PV: O(32q x 128d) += P(32x64) @ V(64x128);  V from Vsm=[d][key]
#pragma unroll
    for (int ks = 0; ks < 2; ++ks) {
      bf16x8 pa[2];
#pragma unroll
      for (int pm = 0; pm < 2; ++pm)
        pa[pm] = *(const bf16x8*)&Psm[w][(pm * 16 + lr) * 72 + ks * 32 + lg * 8];
#pragma unroll
      for (int nd = 0; nd < 8; ++nd) {
        bf16x8 vb = *(const bf16x8*)&Vsm[(nd * 16 + lr) * 72 + ks * 32 + lg * 8];
#pragma unroll
        for (int pm = 0; pm < 2; ++pm)
          acc_o[pm][nd] = __builtin_amdgcn_mfma_f32_16x16x32_bf16(pa[pm], vb, acc_o[pm][nd], 0, 0, 0);
      }
    }
  }

  // epilogue: O /= l, store bf16 at (b, q, h, d)
  if (lg == 0) {
    Alds[w][lr] = 1.f / l_run[0];
    Alds[w][16 + lr] = 1.f / l_run[1];
  }
  f32x4 li0 = *(const f32x4*)&Alds[w][lg * 4];
  f32x4 li1 = *(const f32x4*)&Alds[w][16 + lg * 4];
  unsigned short* Ob = Om + ((size_t)(b * SLEN + q0) * NH + h) * HD;
#pragma unroll
  for (int pm = 0; pm < 2; ++pm)
#pragma unroll
    for (int nd = 0; nd < 8; ++nd)
#pragma unroll
      for (int r = 0; r < 4; ++r) {
        int qq = pm * 16 + lg * 4 + r;
        float v = acc_o[pm][nd][r] * (pm ? li1[r] : li0[r]);
        Ob[(size_t)qq * (NH * HD) + nd * 16 + lr] = f2bf(v);
      }
}

// ---------------------------------------------------------------------------
// Launcher.  d_in: hidden, attention_mask(unused: known causal), wq, wk, wv, wo
// Workspace layout (bytes, total ~169 MB):
// ---------------------------------------------------------------------------
extern "C" void kernel_launch(void* const* d_in, const int* in_sizes, int n_in,
                              void* d_out, int out_size, void* d_ws, size_t ws_size,
                              hipStream_t stream) {
  const float* hidden = (const float*)d_in[0];
  const float* wq = (const float*)d_in[2];
  const float* wk = (const float*)d_in[3];
  const float* wv = (const float*)d_in[4];
  const float* wo = (const float*)d_in[5];

  char* ws = (char*)d_ws;
  unsigned short* Xbf = (unsigned short*)(ws + 0);          // 32 MB (B*S,4096)
  unsigned short* Qb  = (unsigned short*)(ws + 33554432);   // 32 MB (B*S,4096)
  unsigned short* Ob  = (unsigned short*)(ws + 67108864);   // 32 MB (B*S,4096)
  unsigned short* Wb  = (unsigned short*)(ws + 100663296);  // 32 MB wq, later wo
  unsigned short* Kb  = (unsigned short*)(ws + 134217728);  // 8 MB (B*S,1024)
  unsigned short* Vb  = (unsigned short*)(ws + 142606336);  // 8 MB (B*S,1024)
  unsigned short* VTb = (unsigned short*)(ws + 150994944);  // 8 MB (B,8,128,S)
  unsigned short* Wkb = (unsigned short*)(ws + 159383552);  // 8 MB
  unsigned short* Wvb = (unsigned short*)(ws + 167772160);  // 8 MB
  float* ct = (float*)(ws + 176160768);                     // 0.5 MB
  float* st = (float*)(ws + 176685056);                     // 0.5 MB

  // 1) bf16 casts
  cvt_f32_bf16<<<8192, 256, 0, stream>>>(hidden, Xbf);
  cvt_f32_bf16<<<8192, 256, 0, stream>>>(wq, Wb);
  cvt_f32_bf16<<<2048, 256, 0, stream>>>(wk, Wkb);
  cvt_f32_bf16<<<2048, 256, 0, stream>>>(wv, Wvb);

  // 2) projections
  gemm_bt<unsigned short><<<1024, 256, 0, stream>>>(Xbf, Wb, Qb, 4096, 4096, 4096);
  gemm_bt<unsigned short><<<256, 256, 0, stream>>>(Xbf, Wkb, Kb, 4096, 1024, 4096);
  gemm_bt<unsigned short><<<256, 256, 0, stream>>>(Xbf, Wvb, Vb, 4096, 1024, 4096);

  // 3) RoPE
  rope_tables<<<512, 256, 0, stream>>>(ct, st);
  rope_apply<<<4096, 256, 0, stream>>>(Qb, ct, st, NH);
  rope_apply<<<1024, 256, 0, stream>>>(Kb, ct, st, NKV);

  // 4) V -> V^T for contiguous PV B-fragments
  transpose_v<<<dim3(64, 16), 256, 0, stream>>>(Vb, VTb);

  // 5) causal GQA flash attention
  attn_fwd<<<dim3(SLEN / 32, NKV, BATCH), 256, 0, stream>>>(Qb, Kb, VTb, Ob);

  // 6) output projection (fp32 out)
  cvt_f32_bf16<<<8192, 256, 0, stream>>>(wo, Wb);
  gemm_bt<float><<<1024, 256, 0, stream>>>(Ob, Wb, (float*)d_out, 4096, 4096, 4096);
}